// Round 18
// baseline (616.468 us; speedup 1.0000x reference)
//
#include <hip/hip_runtime.h>
#include <hip/hip_fp16.h>

// DAG phenotype evaluation: sentinel dataflow + watermark + static ownership
// + prefetch-under-poll + distributed counters + PROBE-THEN-GATHER POLL (r18).
//
// r17 (NW=8192, exact-capacity residency) HUNG: the all-waves-resident
// requirement had zero slack. Lesson: keep >=2x occupancy headroom. Back to
// NW=4096 (r16, 472us, proven).
//
// r18's one change (inside the poll only; asm prefetch block is
// byte-identical to r16): poll retries PROBE word 0 of each missing row
// with all 64 lanes at the SAME address -> one 4B request per row per
// generation instead of a 256B full-row re-gather. ~4000 in-poll waves were
// pushing ~4 TB/s of full-row coherent reloads -> L3-path congestion ->
// ~3us hops (472us / ~150-deep chain). Probe cuts poll traffic ~64x; the
// full coherent re-gather happens once per row, after the probe flips.
// Self-verifying: the top-of-loop full-row sentinel check keeps a row in
// `need` if ANY lane still sees NaN (handles word-arrival skew exactly);
// re-probe succeeds immediately and re-gathers. No asm in the poll (all
// __hip_atomic_load, compiler-managed) -> immune to the r13-r15
// in-flight-asm-spill corruption class.
//
// Structure: wave w of NW=4096 owns nodes N_IN + w + t*NW (24 rounds);
// 1024 blocks x 4 waves = 4/CU vs >=8/CU capacity -> all resident with
// headroom. Per iteration ONE top vmcnt(0) + sentinel poll. Preds < WM
// (stale lower bound = safe): PLAIN cached loads; preds >= WM: coherent
// (sc0 sc1) loads + poll. Publish: sc0 sc1 write-through store. Two-level
// distributed page counters -> subs_done -> WM CAS; WM replicated over 32
// lines (monotone; races leave lower = safe).
//
// vals[N_NODES][64]: packed half2(b, b+64), 256 B/row; SENTW = NaN|NaN =
// "not ready" (no real value is NaN: inputs finite, outputs relu>=0).

#define N_NODES 100000
#define N_IN    1024
#define N_OUT   1024
#define FAN_IN  32
#define NPAIR   64
#define N_TODO  (N_NODES - N_IN)
#define SENTW   0xFFFFFFFFu
#define NW      4096
#define NBLK    (NW / 4)        // 1024 blocks
#define PGSZ    1024
#define PGSHIFT 10
#define NPAGES  ((N_TODO + PGSZ - 1) / PGSZ)   // 97
#define NSUB    32
#define WMREP   32

#define OFS_WM    4096
#define OFS_SD    16384
#define OFS_SUB   65536
#define OFS_VALS  860160
#define LSTRIDE   64

__device__ __forceinline__ int subq(int pg) {
    return min(PGSZ, N_TODO - (pg << PGSHIFT)) >> 5;   // 32, last page 21
}

__global__ __launch_bounds__(256) void init_kernel(const float* __restrict__ x,
                                                   unsigned* __restrict__ vals,
                                                   int* __restrict__ wm,
                                                   int* __restrict__ subs_done,
                                                   int* __restrict__ sub_cnt) {
    const int tid = blockIdx.x * blockDim.x + threadIdx.x;
    if (tid < WMREP)         wm[tid * LSTRIDE] = 0;
    if (tid < NPAGES)        subs_done[tid * LSTRIDE] = 0;
    if (tid < NPAGES * NSUB) sub_cnt[tid * LSTRIDE] = 0;
    if (tid < N_IN * NPAIR) {
        const int i = tid >> 6;
        const int b = tid & 63;
        __half2 h2 = __floats2half2_rn(x[b * N_IN + i], x[(b + 64) * N_IN + i]);
        vals[i * NPAIR + b] = *reinterpret_cast<unsigned*>(&h2);
    }
    uint4* p = (uint4*)(vals + (size_t)N_IN * NPAIR);
    const int total = N_TODO * NPAIR / 4;
    const uint4 s4 = make_uint4(SENTW, SENTW, SENTW, SENTW);
    for (int t = tid; t < total; t += gridDim.x * blockDim.x)
        p[t] = s4;
}

__device__ __forceinline__ void wm_advance(int* wm, int* subs_done) {
    for (;;) {   // advance master WM over all consecutively-complete pages
        int cur = __hip_atomic_load(wm, __ATOMIC_RELAXED, __HIP_MEMORY_SCOPE_AGENT);
        if (cur >= NPAGES) break;
        int sd = __hip_atomic_load(subs_done + (size_t)cur * LSTRIDE,
                                   __ATOMIC_RELAXED, __HIP_MEMORY_SCOPE_AGENT);
        if (sd < NSUB) break;
        int expected = cur;
        __hip_atomic_compare_exchange_strong(wm, &expected, cur + 1,
                                             __ATOMIC_RELAXED, __ATOMIC_RELAXED,
                                             __HIP_MEMORY_SCOPE_AGENT);
    }
    int fin = __hip_atomic_load(wm, __ATOMIC_RELAXED, __HIP_MEMORY_SCOPE_AGENT);
    for (int r = 1; r < WMREP; ++r)
        __hip_atomic_store(wm + (size_t)r * LSTRIDE, fin,
                           __ATOMIC_RELAXED, __HIP_MEMORY_SCOPE_AGENT);
}

__global__ __launch_bounds__(256, 2) void dag_kernel(const float* __restrict__ weights,
                                                     const int* __restrict__ in_ids,
                                                     unsigned* __restrict__ vals,
                                                     int* __restrict__ wm,
                                                     int* __restrict__ subs_done,
                                                     int* __restrict__ sub_cnt,
                                                     float* __restrict__ out) {
    const int tid  = threadIdx.x;
    const int lane = tid & 63;
    const int w    = __builtin_amdgcn_readfirstlane(blockIdx.x * 4 + (tid >> 6));
    const int g    = w & (NSUB - 1);                 // sub-counter group
    int* wm_rep    = wm + (size_t)(blockIdx.x & (WMREP - 1)) * LSTRIDE;

    unsigned v[FAN_IN];          // current node's gathered pred values
    unsigned vn[FAN_IN];         // prefetch buffer
    unsigned wmv  = 0;           // asm-loaded wm replica (valid after top drain)
    unsigned cohm = 0, cmn = 0;  // uniform coherent-path bitmasks (cur / next)
    int pend_pg = -1, pend_old = 0;

    int node = N_IN + w;         // first own node

    // prologue: issue gather(first) into vn with wmn = N_IN
    {
        const long wb = (long)node * FAN_IN;
#pragma unroll
        for (int k = 0; k < FAN_IN; ++k) {
            const int id = in_ids[wb + k];
            const unsigned* p = vals + (long)id * NPAIR + lane;
            if (id < N_IN) {
                asm volatile("global_load_dword %0, %1, off"
                             : "=v"(vn[k]) : "v"(p));
            } else {
                asm volatile("global_load_dword %0, %1, off sc0 sc1"
                             : "=v"(vn[k]) : "v"(p));
                cmn |= 1u << k;
            }
        }
        asm volatile("global_load_dword %0, %1, off sc0 sc1"
                     : "=v"(wmv) : "v"(wm_rep));
    }

    for (;;) {
        // single wait: drains prefetch(vn)+WM (issued one iter ago), prev
        // publish stores, and the sub atomic before that.
        asm volatile("s_waitcnt vmcnt(0)" ::: "memory");
        __builtin_amdgcn_sched_barrier(0);

        // promote prefetch buffer to working buffer
#pragma unroll
        for (int k = 0; k < FAN_IN; ++k) v[k] = vn[k];
        cohm = cmn;

        // deferred sub-fill check (atomic issued last iter, result drained)
        if (pend_pg >= 0) {
            if (lane == 0 && pend_old + 1 == subq(pend_pg)) {
                int sd = __hip_atomic_fetch_add(subs_done + (size_t)pend_pg * LSTRIDE, 1,
                                                __ATOMIC_RELAXED, __HIP_MEMORY_SCOPE_AGENT);
                if (sd + 1 == NSUB) wm_advance(wm, subs_done);
            }
            pend_pg = -1;
        }
        // issue sub atomic for PREVIOUS own node (its stores are drained)
        if (node - NW >= N_IN) {
            const int ppg = (node - NW - N_IN) >> PGSHIFT;
            if (lane == 0)
                pend_old = __hip_atomic_fetch_add(
                    sub_cnt + ((size_t)ppg * NSUB + g) * LSTRIDE, 1,
                    __ATOMIC_RELAXED, __HIP_MEMORY_SCOPE_AGENT);
            pend_pg = ppg;
        }

        // WM for classifying the NEXT node's gather (one iter stale = safe)
        const int wmn = __builtin_amdgcn_readfirstlane((int)(N_IN + (wmv << PGSHIFT)));

        // issue prefetch gather(next) into vn NOW — hides under poll(cur)
        const int nxt = node + NW;
        cmn = 0;
        if (nxt < N_NODES) {
            const long wbn = (long)nxt * FAN_IN;
#pragma unroll
            for (int k = 0; k < FAN_IN; ++k) {
                const int id = in_ids[wbn + k];
                const unsigned* p = vals + (long)id * NPAIR + lane;
                if (id < wmn) {
                    asm volatile("global_load_dword %0, %1, off"
                                 : "=v"(vn[k]) : "v"(p));
                } else {
                    asm volatile("global_load_dword %0, %1, off sc0 sc1"
                                 : "=v"(vn[k]) : "v"(p));
                    cmn |= 1u << k;
                }
            }
            asm volatile("global_load_dword %0, %1, off sc0 sc1"
                         : "=v"(wmv) : "v"(wm_rep));
        }

        const long wb = (long)node * FAN_IN;

        // sentinel poll: probe-then-gather. Full-row check at loop top is
        // the verifier; probes are 1-word same-address loads (one request
        // per row per generation, ~64x less traffic than full re-gather).
        unsigned need = cohm;
        while (need) {
            unsigned got = 0;
#pragma unroll
            for (int k = 0; k < FAN_IN; ++k)
                if ((need >> k) & 1u)
                    if (__all(v[k] != SENTW)) got |= 1u << k;
            need &= ~got;
            if (!need) break;

            // probe phase: word 0 of each missing row, all lanes same addr
            unsigned ready = 0;
            for (;;) {
#pragma unroll
                for (int k = 0; k < FAN_IN; ++k)
                    if ((need >> k) & 1u) {
                        const int id = in_ids[wb + k];
                        unsigned pw = __hip_atomic_load(vals + (long)id * NPAIR,
                                                        __ATOMIC_RELAXED,
                                                        __HIP_MEMORY_SCOPE_AGENT);
                        if (pw != SENTW) ready |= 1u << k;
                    }
                if (ready) break;
                __builtin_amdgcn_s_sleep(1);
            }

            // full coherent re-gather of probe-ready rows; top-of-loop
            // check verifies every lane (straggler words keep row in need)
#pragma unroll
            for (int k = 0; k < FAN_IN; ++k)
                if ((ready >> k) & 1u) {
                    const int id = in_ids[wb + k];
                    v[k] = __hip_atomic_load(vals + (long)id * NPAIR + lane,
                                             __ATOMIC_RELAXED,
                                             __HIP_MEMORY_SCOPE_AGENT);
                }
        }

        // dot + relu in fp32 (weights uniform -> SGPR operand)
        float acc0 = 0.f, acc1 = 0.f;
#pragma unroll
        for (int k = 0; k < FAN_IN; ++k) {
            const float  wk = weights[wb + k];
            const __half2 h2 = *reinterpret_cast<const __half2*>(&v[k]);
            const float2  f  = __half22float2(h2);
            acc0 = fmaf(wk, f.x, acc0);
            acc1 = fmaf(wk, f.y, acc1);
        }
        acc0 = fmaxf(acc0, 0.f);
        acc1 = fmaxf(acc1, 0.f);

        // publish (agent-coherent write-through store; drained at next top)
        __half2 hr = __floats2half2_rn(acc0, acc1);
        const unsigned ow = *reinterpret_cast<const unsigned*>(&hr);
        unsigned* orow = vals + (long)node * NPAIR + lane;
        asm volatile("global_store_dword %0, %1, off sc0 sc1"
                     :: "v"(orow), "v"(ow));

        // output-layer scatter
        if (node >= N_NODES - N_OUT) {
            const int jo = node - (N_NODES - N_OUT);
            out[lane * N_OUT + jo]        = acc0;
            out[(lane + 64) * N_OUT + jo] = acc1;
        }

        if (nxt >= N_NODES) break;
        node = nxt;
    }

    // epilogue: drain last publish, flush pending + last node's count
    asm volatile("s_waitcnt vmcnt(0)" ::: "memory");
    if (lane == 0) {
        if (pend_pg >= 0 && pend_old + 1 == subq(pend_pg)) {
            int sd = __hip_atomic_fetch_add(subs_done + (size_t)pend_pg * LSTRIDE, 1,
                                            __ATOMIC_RELAXED, __HIP_MEMORY_SCOPE_AGENT);
            if (sd + 1 == NSUB) wm_advance(wm, subs_done);
        }
        const int pg = (node - N_IN) >> PGSHIFT;
        int old = __hip_atomic_fetch_add(sub_cnt + ((size_t)pg * NSUB + g) * LSTRIDE, 1,
                                         __ATOMIC_RELAXED, __HIP_MEMORY_SCOPE_AGENT);
        if (old + 1 == subq(pg)) {
            int sd = __hip_atomic_fetch_add(subs_done + (size_t)pg * LSTRIDE, 1,
                                            __ATOMIC_RELAXED, __HIP_MEMORY_SCOPE_AGENT);
            if (sd + 1 == NSUB) wm_advance(wm, subs_done);
        }
    }
}

extern "C" void kernel_launch(void* const* d_in, const int* in_sizes, int n_in,
                              void* d_out, int out_size, void* d_ws, size_t ws_size,
                              hipStream_t stream) {
    const float* x       = (const float*)d_in[0];
    const float* weights = (const float*)d_in[1];
    const int*   in_ids  = (const int*)d_in[2];
    float*       out     = (float*)d_out;

    int*      wm       = (int*)((char*)d_ws + OFS_WM);
    int*      subs_done= (int*)((char*)d_ws + OFS_SD);
    int*      sub_cnt  = (int*)((char*)d_ws + OFS_SUB);
    unsigned* vals     = (unsigned*)((char*)d_ws + OFS_VALS);

    init_kernel<<<2048, 256, 0, stream>>>(x, vals, wm, subs_done, sub_cnt);
    // 1024 blocks x 4 waves = NW=4096; 4 blocks/CU vs >=8/CU capacity ->
    // all waves resident WITH HEADROOM (r17 lesson: never exact-capacity).
    dag_kernel<<<NBLK, 256, 0, stream>>>(weights, in_ids, vals,
                                         wm, subs_done, sub_cnt, out);
}

// Round 19
// 557.336 us; speedup vs baseline: 1.1061x; 1.1061x over previous
//
#include <hip/hip_runtime.h>
#include <hip/hip_fp16.h>

// DAG phenotype evaluation: sentinel dataflow + watermark + static ownership
// + prefetch-under-poll + distributed counters (round 19 = r16 code with
// NW=6144 and no-sleep poll).
//
// Calibration from r18 (+144us for one extra RT per chain hop): critical
// chain D ~ 150 hops, coherent RT ~ 1us. dur ~ serial-rounds + D x hop,
// hop ~ 3us (phase + RT + publish flight). Sub-RT detect pipelines (r12-r15)
// all failed on correctness (in-flight asm "=v" spill corruption class);
// traffic reduction (r18) proved useless. Remaining safe levers:
//   1) NW=6144: 1536 blocks = 6/CU vs 8/CU capacity (512-block slack;
//      r17's exact-capacity hang avoided). Rounds/wave 24 -> ~16.
//   2) no s_sleep in the poll: generations are RT-bound; sleep only added
//      wake latency on every critical hop. Retry traffic stays bounded
//      (only missing rows reload).
//
// Structure (r11/r16 proven): wave w of NW owns nodes N_IN + w + t*NW.
// Per iteration ONE top vmcnt(0) (drains the 33-load asm prefetch issued an
// iteration ago, prev publish stores, prev sub atomic) + sentinel poll.
// Preds < WM (stale lower bound = safe): PLAIN cached loads (L2);
// preds >= WM: agent-coherent loads (sc0 sc1) + poll. Publish: sc0 sc1
// write-through store. Two-level distributed page counters (32 sub-lines
// per page; quota 32, last page 21) -> subs_done -> WM CAS; WM replicated
// over 32 lines (monotone; races leave lower = safe).
//
// vals[N_NODES][64]: packed half2(b, b+64), 256 B/row; SENTW = NaN|NaN =
// "not ready" (no real value is NaN: inputs finite, outputs relu>=0).
//
// Deadlock-freedom: all 1536 blocks resident (capacity 2048 with 40 VGPR /
// 0 LDS); waves process own nodes in increasing order; the lowest
// uncomputed node's preds are all computed, so its poll terminates ->
// induction. WM lag cannot deadlock (polls are correct with WM == 0).

#define N_NODES 100000
#define N_IN    1024
#define N_OUT   1024
#define FAN_IN  32
#define NPAIR   64
#define N_TODO  (N_NODES - N_IN)
#define SENTW   0xFFFFFFFFu
#define NW      6144
#define NBLK    (NW / 4)        // 1536 blocks
#define PGSZ    1024
#define PGSHIFT 10
#define NPAGES  ((N_TODO + PGSZ - 1) / PGSZ)   // 97
#define NSUB    32
#define WMREP   32

#define OFS_WM    4096
#define OFS_SD    16384
#define OFS_SUB   65536
#define OFS_VALS  860160
#define LSTRIDE   64

__device__ __forceinline__ int subq(int pg) {
    return min(PGSZ, N_TODO - (pg << PGSHIFT)) >> 5;   // 32, last page 21
}

__global__ __launch_bounds__(256) void init_kernel(const float* __restrict__ x,
                                                   unsigned* __restrict__ vals,
                                                   int* __restrict__ wm,
                                                   int* __restrict__ subs_done,
                                                   int* __restrict__ sub_cnt) {
    const int tid = blockIdx.x * blockDim.x + threadIdx.x;
    if (tid < WMREP)         wm[tid * LSTRIDE] = 0;
    if (tid < NPAGES)        subs_done[tid * LSTRIDE] = 0;
    if (tid < NPAGES * NSUB) sub_cnt[tid * LSTRIDE] = 0;
    if (tid < N_IN * NPAIR) {
        const int i = tid >> 6;
        const int b = tid & 63;
        __half2 h2 = __floats2half2_rn(x[b * N_IN + i], x[(b + 64) * N_IN + i]);
        vals[i * NPAIR + b] = *reinterpret_cast<unsigned*>(&h2);
    }
    uint4* p = (uint4*)(vals + (size_t)N_IN * NPAIR);
    const int total = N_TODO * NPAIR / 4;
    const uint4 s4 = make_uint4(SENTW, SENTW, SENTW, SENTW);
    for (int t = tid; t < total; t += gridDim.x * blockDim.x)
        p[t] = s4;
}

__device__ __forceinline__ void wm_advance(int* wm, int* subs_done) {
    for (;;) {   // advance master WM over all consecutively-complete pages
        int cur = __hip_atomic_load(wm, __ATOMIC_RELAXED, __HIP_MEMORY_SCOPE_AGENT);
        if (cur >= NPAGES) break;
        int sd = __hip_atomic_load(subs_done + (size_t)cur * LSTRIDE,
                                   __ATOMIC_RELAXED, __HIP_MEMORY_SCOPE_AGENT);
        if (sd < NSUB) break;
        int expected = cur;
        __hip_atomic_compare_exchange_strong(wm, &expected, cur + 1,
                                             __ATOMIC_RELAXED, __ATOMIC_RELAXED,
                                             __HIP_MEMORY_SCOPE_AGENT);
    }
    int fin = __hip_atomic_load(wm, __ATOMIC_RELAXED, __HIP_MEMORY_SCOPE_AGENT);
    for (int r = 1; r < WMREP; ++r)
        __hip_atomic_store(wm + (size_t)r * LSTRIDE, fin,
                           __ATOMIC_RELAXED, __HIP_MEMORY_SCOPE_AGENT);
}

__global__ __launch_bounds__(256, 2) void dag_kernel(const float* __restrict__ weights,
                                                     const int* __restrict__ in_ids,
                                                     unsigned* __restrict__ vals,
                                                     int* __restrict__ wm,
                                                     int* __restrict__ subs_done,
                                                     int* __restrict__ sub_cnt,
                                                     float* __restrict__ out) {
    const int tid  = threadIdx.x;
    const int lane = tid & 63;
    const int w    = __builtin_amdgcn_readfirstlane(blockIdx.x * 4 + (tid >> 6));
    const int g    = w & (NSUB - 1);                 // sub-counter group
    int* wm_rep    = wm + (size_t)(blockIdx.x & (WMREP - 1)) * LSTRIDE;

    unsigned v[FAN_IN];          // current node's gathered pred values
    unsigned vn[FAN_IN];         // prefetch buffer
    unsigned wmv  = 0;           // asm-loaded wm replica (valid after top drain)
    unsigned cohm = 0, cmn = 0;  // uniform coherent-path bitmasks (cur / next)
    int pend_pg = -1, pend_old = 0;

    int node = N_IN + w;         // first own node

    // prologue: issue gather(first) into vn with wmn = N_IN
    {
        const long wb = (long)node * FAN_IN;
#pragma unroll
        for (int k = 0; k < FAN_IN; ++k) {
            const int id = in_ids[wb + k];
            const unsigned* p = vals + (long)id * NPAIR + lane;
            if (id < N_IN) {
                asm volatile("global_load_dword %0, %1, off"
                             : "=v"(vn[k]) : "v"(p));
            } else {
                asm volatile("global_load_dword %0, %1, off sc0 sc1"
                             : "=v"(vn[k]) : "v"(p));
                cmn |= 1u << k;
            }
        }
        asm volatile("global_load_dword %0, %1, off sc0 sc1"
                     : "=v"(wmv) : "v"(wm_rep));
    }

    for (;;) {
        // single wait: drains prefetch(vn)+WM (issued one iter ago), prev
        // publish stores, and the sub atomic before that.
        asm volatile("s_waitcnt vmcnt(0)" ::: "memory");
        __builtin_amdgcn_sched_barrier(0);

        // promote prefetch buffer to working buffer
#pragma unroll
        for (int k = 0; k < FAN_IN; ++k) v[k] = vn[k];
        cohm = cmn;

        // deferred sub-fill check (atomic issued last iter, result drained)
        if (pend_pg >= 0) {
            if (lane == 0 && pend_old + 1 == subq(pend_pg)) {
                int sd = __hip_atomic_fetch_add(subs_done + (size_t)pend_pg * LSTRIDE, 1,
                                                __ATOMIC_RELAXED, __HIP_MEMORY_SCOPE_AGENT);
                if (sd + 1 == NSUB) wm_advance(wm, subs_done);
            }
            pend_pg = -1;
        }
        // issue sub atomic for PREVIOUS own node (its stores are drained)
        if (node - NW >= N_IN) {
            const int ppg = (node - NW - N_IN) >> PGSHIFT;
            if (lane == 0)
                pend_old = __hip_atomic_fetch_add(
                    sub_cnt + ((size_t)ppg * NSUB + g) * LSTRIDE, 1,
                    __ATOMIC_RELAXED, __HIP_MEMORY_SCOPE_AGENT);
            pend_pg = ppg;
        }

        // WM for classifying the NEXT node's gather (one iter stale = safe)
        const int wmn = __builtin_amdgcn_readfirstlane((int)(N_IN + (wmv << PGSHIFT)));

        // issue prefetch gather(next) into vn NOW — hides under poll(cur)
        const int nxt = node + NW;
        cmn = 0;
        if (nxt < N_NODES) {
            const long wbn = (long)nxt * FAN_IN;
#pragma unroll
            for (int k = 0; k < FAN_IN; ++k) {
                const int id = in_ids[wbn + k];
                const unsigned* p = vals + (long)id * NPAIR + lane;
                if (id < wmn) {
                    asm volatile("global_load_dword %0, %1, off"
                                 : "=v"(vn[k]) : "v"(p));
                } else {
                    asm volatile("global_load_dword %0, %1, off sc0 sc1"
                                 : "=v"(vn[k]) : "v"(p));
                    cmn |= 1u << k;
                }
            }
            asm volatile("global_load_dword %0, %1, off sc0 sc1"
                         : "=v"(wmv) : "v"(wm_rep));
        }

        const long wb = (long)node * FAN_IN;

        // sentinel poll over the coherent subset (irreducible dependency
        // wait). No s_sleep: generations are RT-bound; sleep only added
        // detect latency on every critical hop.
        unsigned need = cohm;
        while (need) {
            unsigned got = 0;
#pragma unroll
            for (int k = 0; k < FAN_IN; ++k)
                if ((need >> k) & 1u)
                    if (__all(v[k] != SENTW)) got |= 1u << k;
            need &= ~got;
            if (!need) break;
#pragma unroll
            for (int k = 0; k < FAN_IN; ++k)
                if ((need >> k) & 1u) {
                    const int id = in_ids[wb + k];
                    v[k] = __hip_atomic_load(vals + (long)id * NPAIR + lane,
                                             __ATOMIC_RELAXED,
                                             __HIP_MEMORY_SCOPE_AGENT);
                }
        }

        // dot + relu in fp32 (weights uniform -> SGPR operand)
        float acc0 = 0.f, acc1 = 0.f;
#pragma unroll
        for (int k = 0; k < FAN_IN; ++k) {
            const float  wk = weights[wb + k];
            const __half2 h2 = *reinterpret_cast<const __half2*>(&v[k]);
            const float2  f  = __half22float2(h2);
            acc0 = fmaf(wk, f.x, acc0);
            acc1 = fmaf(wk, f.y, acc1);
        }
        acc0 = fmaxf(acc0, 0.f);
        acc1 = fmaxf(acc1, 0.f);

        // publish (agent-coherent write-through store; drained at next top)
        __half2 hr = __floats2half2_rn(acc0, acc1);
        const unsigned ow = *reinterpret_cast<const unsigned*>(&hr);
        unsigned* orow = vals + (long)node * NPAIR + lane;
        asm volatile("global_store_dword %0, %1, off sc0 sc1"
                     :: "v"(orow), "v"(ow));

        // output-layer scatter
        if (node >= N_NODES - N_OUT) {
            const int jo = node - (N_NODES - N_OUT);
            out[lane * N_OUT + jo]        = acc0;
            out[(lane + 64) * N_OUT + jo] = acc1;
        }

        if (nxt >= N_NODES) break;
        node = nxt;
    }

    // epilogue: drain last publish, flush pending + last node's count
    asm volatile("s_waitcnt vmcnt(0)" ::: "memory");
    if (lane == 0) {
        if (pend_pg >= 0 && pend_old + 1 == subq(pend_pg)) {
            int sd = __hip_atomic_fetch_add(subs_done + (size_t)pend_pg * LSTRIDE, 1,
                                            __ATOMIC_RELAXED, __HIP_MEMORY_SCOPE_AGENT);
            if (sd + 1 == NSUB) wm_advance(wm, subs_done);
        }
        const int pg = (node - N_IN) >> PGSHIFT;
        int old = __hip_atomic_fetch_add(sub_cnt + ((size_t)pg * NSUB + g) * LSTRIDE, 1,
                                         __ATOMIC_RELAXED, __HIP_MEMORY_SCOPE_AGENT);
        if (old + 1 == subq(pg)) {
            int sd = __hip_atomic_fetch_add(subs_done + (size_t)pg * LSTRIDE, 1,
                                            __ATOMIC_RELAXED, __HIP_MEMORY_SCOPE_AGENT);
            if (sd + 1 == NSUB) wm_advance(wm, subs_done);
        }
    }
}

extern "C" void kernel_launch(void* const* d_in, const int* in_sizes, int n_in,
                              void* d_out, int out_size, void* d_ws, size_t ws_size,
                              hipStream_t stream) {
    const float* x       = (const float*)d_in[0];
    const float* weights = (const float*)d_in[1];
    const int*   in_ids  = (const int*)d_in[2];
    float*       out     = (float*)d_out;

    int*      wm       = (int*)((char*)d_ws + OFS_WM);
    int*      subs_done= (int*)((char*)d_ws + OFS_SD);
    int*      sub_cnt  = (int*)((char*)d_ws + OFS_SUB);
    unsigned* vals     = (unsigned*)((char*)d_ws + OFS_VALS);

    init_kernel<<<2048, 256, 0, stream>>>(x, vals, wm, subs_done, sub_cnt);
    // 1536 blocks x 4 waves = NW=6144; 6 blocks/CU vs 8/CU capacity ->
    // all waves resident with 512-block slack (r17 lesson).
    dag_kernel<<<NBLK, 256, 0, stream>>>(weights, in_ids, vals,
                                         wm, subs_done, sub_cnt, out);
}

// Round 20
// 470.223 us; speedup vs baseline: 1.3110x; 1.1853x over previous
//
#include <hip/hip_runtime.h>
#include <hip/hip_fp16.h>

// DAG phenotype evaluation: sentinel dataflow + watermark + static ownership
// + prefetch-under-poll + distributed counters (round 20 = exact r16 restore,
// the measured optimum: NW=4096, s_sleep(1) poll, 472us).
//
// Exploration summary (all measured on MI355X):
//   NW: 2048=525us, 4096=472us, 6144=557us (poll-population congestion),
//       8192=hang (exact-capacity residency). NW=4096 is the optimum of the
//       serial-rounds vs coherent-RT-congestion tradeoff.
//   Poll variants: flat/lgkm decouple 569us (flat retires lgkmcnt at addr
//       translation); 2-deep asm pipeline & deferred-prefetch = silent
//       corruption (allocator spills in-flight asm "=v" destinations);
//       probe-then-gather 616us (+1 RT per chain hop: calibrates RT~1us,
//       D~150); no-sleep (confounded with NW=6144) regressed.
//   Control-plane: claim counter=1291us, chunk-serial=2806us,
//       block-lockstep=1428us; static ownership + distributed two-level
//       page counters + replicated WM is the best protocol found.
//
// Remaining time = latency floor of this protocol: ~150 serial publish->
// detect coherent round-trips (~1us each under load) + ~24 rounds/wave of
// pipelined per-node work. HBM 8%, VALU 11% -> no classical roofline.
//
// Structure: wave w of NW=4096 owns nodes N_IN + w + t*NW (24 rounds);
// 1024 blocks x 4 waves = 4/CU vs 8/CU capacity -> all resident WITH slack.
// Per iteration ONE top vmcnt(0) (drains the 33-load asm prefetch issued an
// iteration ago, prev publish stores, prev sub atomic) + sentinel poll.
// Preds < WM (stale lower bound = safe): PLAIN cached loads (L2);
// preds >= WM: agent-coherent loads (sc0 sc1) + poll w/ s_sleep backoff.
// Publish: sc0 sc1 write-through store. Two-level distributed page counters
// (32 sub-lines/page; quota 32, last page 21) -> subs_done -> WM CAS; WM
// replicated over 32 lines (monotone; races leave lower = safe value).
//
// vals[N_NODES][64]: packed half2(b, b+64), 256 B/row; SENTW = NaN|NaN =
// "not ready" (no real value is NaN: inputs finite, outputs relu>=0).
//
// Deadlock-freedom: all waves resident; own nodes processed in increasing
// order; the lowest uncomputed node's preds are all computed, so its poll
// terminates -> induction. WM lag cannot deadlock (polls correct w/ WM=0).

#define N_NODES 100000
#define N_IN    1024
#define N_OUT   1024
#define FAN_IN  32
#define NPAIR   64
#define N_TODO  (N_NODES - N_IN)
#define SENTW   0xFFFFFFFFu
#define NW      4096
#define NBLK    (NW / 4)        // 1024 blocks
#define PGSZ    1024
#define PGSHIFT 10
#define NPAGES  ((N_TODO + PGSZ - 1) / PGSZ)   // 97
#define NSUB    32
#define WMREP   32

#define OFS_WM    4096
#define OFS_SD    16384
#define OFS_SUB   65536
#define OFS_VALS  860160
#define LSTRIDE   64

__device__ __forceinline__ int subq(int pg) {
    return min(PGSZ, N_TODO - (pg << PGSHIFT)) >> 5;   // 32, last page 21
}

__global__ __launch_bounds__(256) void init_kernel(const float* __restrict__ x,
                                                   unsigned* __restrict__ vals,
                                                   int* __restrict__ wm,
                                                   int* __restrict__ subs_done,
                                                   int* __restrict__ sub_cnt) {
    const int tid = blockIdx.x * blockDim.x + threadIdx.x;
    if (tid < WMREP)         wm[tid * LSTRIDE] = 0;
    if (tid < NPAGES)        subs_done[tid * LSTRIDE] = 0;
    if (tid < NPAGES * NSUB) sub_cnt[tid * LSTRIDE] = 0;
    if (tid < N_IN * NPAIR) {
        const int i = tid >> 6;
        const int b = tid & 63;
        __half2 h2 = __floats2half2_rn(x[b * N_IN + i], x[(b + 64) * N_IN + i]);
        vals[i * NPAIR + b] = *reinterpret_cast<unsigned*>(&h2);
    }
    uint4* p = (uint4*)(vals + (size_t)N_IN * NPAIR);
    const int total = N_TODO * NPAIR / 4;
    const uint4 s4 = make_uint4(SENTW, SENTW, SENTW, SENTW);
    for (int t = tid; t < total; t += gridDim.x * blockDim.x)
        p[t] = s4;
}

__device__ __forceinline__ void wm_advance(int* wm, int* subs_done) {
    for (;;) {   // advance master WM over all consecutively-complete pages
        int cur = __hip_atomic_load(wm, __ATOMIC_RELAXED, __HIP_MEMORY_SCOPE_AGENT);
        if (cur >= NPAGES) break;
        int sd = __hip_atomic_load(subs_done + (size_t)cur * LSTRIDE,
                                   __ATOMIC_RELAXED, __HIP_MEMORY_SCOPE_AGENT);
        if (sd < NSUB) break;
        int expected = cur;
        __hip_atomic_compare_exchange_strong(wm, &expected, cur + 1,
                                             __ATOMIC_RELAXED, __ATOMIC_RELAXED,
                                             __HIP_MEMORY_SCOPE_AGENT);
    }
    int fin = __hip_atomic_load(wm, __ATOMIC_RELAXED, __HIP_MEMORY_SCOPE_AGENT);
    for (int r = 1; r < WMREP; ++r)
        __hip_atomic_store(wm + (size_t)r * LSTRIDE, fin,
                           __ATOMIC_RELAXED, __HIP_MEMORY_SCOPE_AGENT);
}

__global__ __launch_bounds__(256, 2) void dag_kernel(const float* __restrict__ weights,
                                                     const int* __restrict__ in_ids,
                                                     unsigned* __restrict__ vals,
                                                     int* __restrict__ wm,
                                                     int* __restrict__ subs_done,
                                                     int* __restrict__ sub_cnt,
                                                     float* __restrict__ out) {
    const int tid  = threadIdx.x;
    const int lane = tid & 63;
    const int w    = __builtin_amdgcn_readfirstlane(blockIdx.x * 4 + (tid >> 6));
    const int g    = w & (NSUB - 1);                 // sub-counter group
    int* wm_rep    = wm + (size_t)(blockIdx.x & (WMREP - 1)) * LSTRIDE;

    unsigned v[FAN_IN];          // current node's gathered pred values
    unsigned vn[FAN_IN];         // prefetch buffer
    unsigned wmv  = 0;           // asm-loaded wm replica (valid after top drain)
    unsigned cohm = 0, cmn = 0;  // uniform coherent-path bitmasks (cur / next)
    int pend_pg = -1, pend_old = 0;

    int node = N_IN + w;         // first own node

    // prologue: issue gather(first) into vn with wmn = N_IN
    {
        const long wb = (long)node * FAN_IN;
#pragma unroll
        for (int k = 0; k < FAN_IN; ++k) {
            const int id = in_ids[wb + k];
            const unsigned* p = vals + (long)id * NPAIR + lane;
            if (id < N_IN) {
                asm volatile("global_load_dword %0, %1, off"
                             : "=v"(vn[k]) : "v"(p));
            } else {
                asm volatile("global_load_dword %0, %1, off sc0 sc1"
                             : "=v"(vn[k]) : "v"(p));
                cmn |= 1u << k;
            }
        }
        asm volatile("global_load_dword %0, %1, off sc0 sc1"
                     : "=v"(wmv) : "v"(wm_rep));
    }

    for (;;) {
        // single wait: drains prefetch(vn)+WM (issued one iter ago), prev
        // publish stores, and the sub atomic before that.
        asm volatile("s_waitcnt vmcnt(0)" ::: "memory");
        __builtin_amdgcn_sched_barrier(0);

        // promote prefetch buffer to working buffer
#pragma unroll
        for (int k = 0; k < FAN_IN; ++k) v[k] = vn[k];
        cohm = cmn;

        // deferred sub-fill check (atomic issued last iter, result drained)
        if (pend_pg >= 0) {
            if (lane == 0 && pend_old + 1 == subq(pend_pg)) {
                int sd = __hip_atomic_fetch_add(subs_done + (size_t)pend_pg * LSTRIDE, 1,
                                                __ATOMIC_RELAXED, __HIP_MEMORY_SCOPE_AGENT);
                if (sd + 1 == NSUB) wm_advance(wm, subs_done);
            }
            pend_pg = -1;
        }
        // issue sub atomic for PREVIOUS own node (its stores are drained)
        if (node - NW >= N_IN) {
            const int ppg = (node - NW - N_IN) >> PGSHIFT;
            if (lane == 0)
                pend_old = __hip_atomic_fetch_add(
                    sub_cnt + ((size_t)ppg * NSUB + g) * LSTRIDE, 1,
                    __ATOMIC_RELAXED, __HIP_MEMORY_SCOPE_AGENT);
            pend_pg = ppg;
        }

        // WM for classifying the NEXT node's gather (one iter stale = safe)
        const int wmn = __builtin_amdgcn_readfirstlane((int)(N_IN + (wmv << PGSHIFT)));

        // issue prefetch gather(next) into vn NOW — hides under poll(cur)
        const int nxt = node + NW;
        cmn = 0;
        if (nxt < N_NODES) {
            const long wbn = (long)nxt * FAN_IN;
#pragma unroll
            for (int k = 0; k < FAN_IN; ++k) {
                const int id = in_ids[wbn + k];
                const unsigned* p = vals + (long)id * NPAIR + lane;
                if (id < wmn) {
                    asm volatile("global_load_dword %0, %1, off"
                                 : "=v"(vn[k]) : "v"(p));
                } else {
                    asm volatile("global_load_dword %0, %1, off sc0 sc1"
                                 : "=v"(vn[k]) : "v"(p));
                    cmn |= 1u << k;
                }
            }
            asm volatile("global_load_dword %0, %1, off sc0 sc1"
                         : "=v"(wmv) : "v"(wm_rep));
        }

        const long wb = (long)node * FAN_IN;

        // sentinel poll over the coherent subset (irreducible dependency wait)
        unsigned need = cohm;
        while (need) {
            unsigned got = 0;
#pragma unroll
            for (int k = 0; k < FAN_IN; ++k)
                if ((need >> k) & 1u)
                    if (__all(v[k] != SENTW)) got |= 1u << k;
            need &= ~got;
            if (!need) break;
            __builtin_amdgcn_s_sleep(1);
#pragma unroll
            for (int k = 0; k < FAN_IN; ++k)
                if ((need >> k) & 1u) {
                    const int id = in_ids[wb + k];
                    v[k] = __hip_atomic_load(vals + (long)id * NPAIR + lane,
                                             __ATOMIC_RELAXED,
                                             __HIP_MEMORY_SCOPE_AGENT);
                }
        }

        // dot + relu in fp32 (weights uniform -> SGPR operand)
        float acc0 = 0.f, acc1 = 0.f;
#pragma unroll
        for (int k = 0; k < FAN_IN; ++k) {
            const float  wk = weights[wb + k];
            const __half2 h2 = *reinterpret_cast<const __half2*>(&v[k]);
            const float2  f  = __half22float2(h2);
            acc0 = fmaf(wk, f.x, acc0);
            acc1 = fmaf(wk, f.y, acc1);
        }
        acc0 = fmaxf(acc0, 0.f);
        acc1 = fmaxf(acc1, 0.f);

        // publish (agent-coherent write-through store; drained at next top)
        __half2 hr = __floats2half2_rn(acc0, acc1);
        const unsigned ow = *reinterpret_cast<const unsigned*>(&hr);
        unsigned* orow = vals + (long)node * NPAIR + lane;
        asm volatile("global_store_dword %0, %1, off sc0 sc1"
                     :: "v"(orow), "v"(ow));

        // output-layer scatter
        if (node >= N_NODES - N_OUT) {
            const int jo = node - (N_NODES - N_OUT);
            out[lane * N_OUT + jo]        = acc0;
            out[(lane + 64) * N_OUT + jo] = acc1;
        }

        if (nxt >= N_NODES) break;
        node = nxt;
    }

    // epilogue: drain last publish, flush pending + last node's count
    asm volatile("s_waitcnt vmcnt(0)" ::: "memory");
    if (lane == 0) {
        if (pend_pg >= 0 && pend_old + 1 == subq(pend_pg)) {
            int sd = __hip_atomic_fetch_add(subs_done + (size_t)pend_pg * LSTRIDE, 1,
                                            __ATOMIC_RELAXED, __HIP_MEMORY_SCOPE_AGENT);
            if (sd + 1 == NSUB) wm_advance(wm, subs_done);
        }
        const int pg = (node - N_IN) >> PGSHIFT;
        int old = __hip_atomic_fetch_add(sub_cnt + ((size_t)pg * NSUB + g) * LSTRIDE, 1,
                                         __ATOMIC_RELAXED, __HIP_MEMORY_SCOPE_AGENT);
        if (old + 1 == subq(pg)) {
            int sd = __hip_atomic_fetch_add(subs_done + (size_t)pg * LSTRIDE, 1,
                                            __ATOMIC_RELAXED, __HIP_MEMORY_SCOPE_AGENT);
            if (sd + 1 == NSUB) wm_advance(wm, subs_done);
        }
    }
}

extern "C" void kernel_launch(void* const* d_in, const int* in_sizes, int n_in,
                              void* d_out, int out_size, void* d_ws, size_t ws_size,
                              hipStream_t stream) {
    const float* x       = (const float*)d_in[0];
    const float* weights = (const float*)d_in[1];
    const int*   in_ids  = (const int*)d_in[2];
    float*       out     = (float*)d_out;

    int*      wm       = (int*)((char*)d_ws + OFS_WM);
    int*      subs_done= (int*)((char*)d_ws + OFS_SD);
    int*      sub_cnt  = (int*)((char*)d_ws + OFS_SUB);
    unsigned* vals     = (unsigned*)((char*)d_ws + OFS_VALS);

    init_kernel<<<2048, 256, 0, stream>>>(x, vals, wm, subs_done, sub_cnt);
    // 1024 blocks x 4 waves = NW=4096; 4 blocks/CU vs 8/CU capacity ->
    // all waves resident WITH HEADROOM (r17 lesson: never exact-capacity).
    dag_kernel<<<NBLK, 256, 0, stream>>>(weights, in_ids, vals,
                                         wm, subs_done, sub_cnt, out);
}